// Round 1
// baseline (122.183 us; speedup 1.0000x reference)
//
#include <hip/hip_runtime.h>
#include <math.h>

#define NN 512
#define HW (512*512)
#define CH 3

// D[k][n] = s_k * cos(pi*(2n+1)*k/(2N)), s_0=sqrt(1/N), s_k=sqrt(2/N)
__global__ void k_computeD(float* __restrict__ Dm) {
    int idx = blockIdx.x * blockDim.x + threadIdx.x;   // 0..262143
    int k = idx >> 9, n = idx & 511;
    int m = ((2 * n + 1) * k) & 2047;                  // exact reduction mod 4N
    float s = (k == 0) ? 0.04419417382415922f          // sqrt(1/512)
                       : 0.0625f;                      // sqrt(2/512)
    Dm[idx] = s * cospif((float)m * (1.0f / 1024.0f));
}

// T_row[h][wp] = sum_hp D[hp][h] * att[hp][wp] * rw[hp]
// T_col[h][wp] = cw[wp] * sum_hp D[hp][h] * att[hp][wp]
__global__ void k_stageA(const float* __restrict__ Dm, const float* __restrict__ att,
                         const float* __restrict__ rw, const float* __restrict__ cw,
                         float* __restrict__ Tr, float* __restrict__ Tc) {
    int idx = blockIdx.x * blockDim.x + threadIdx.x;
    int h = idx >> 9, wp = idx & 511;
    float accr = 0.f, accs = 0.f;
    for (int hp = 0; hp < NN; ++hp) {
        float d = Dm[hp * NN + h];          // uniform across block (wp varies)
        float a = att[hp * NN + wp];        // coalesced
        float da = d * a;
        accr += da * rw[hp];
        accs += da;
    }
    Tr[h * NN + wp] = accr;
    Tc[h * NN + wp] = accs * cw[wp];
}

// G[h][w] = sum_wp T[h][wp] * D[wp][w]
__global__ void k_stageB(const float* __restrict__ Dm, const float* __restrict__ Tr,
                         const float* __restrict__ Tc, float* __restrict__ Gr,
                         float* __restrict__ Gc) {
    int idx = blockIdx.x * blockDim.x + threadIdx.x;
    int h = idx >> 9, w = idx & 511;
    float accr = 0.f, accc = 0.f;
    for (int wp = 0; wp < NN; ++wp) {
        float d = Dm[wp * NN + w];          // coalesced across block
        accr += Tr[h * NN + wp] * d;        // uniform across block
        accc += Tc[h * NN + wp] * d;
    }
    Gr[h * NN + w] = accr;
    Gc[h * NN + w] = accc;
}

// Per b: acc_row = sum_{c,hw} x[b,c,hw]*Gr[hw], acc_col same with Gc.
// grid = (16, 64): 16 blocks per batch; each block handles 16384 hw positions.
__global__ void k_reduce(const float* __restrict__ x, const float* __restrict__ Gr,
                         const float* __restrict__ Gc, float* __restrict__ partials) {
    int b = blockIdx.y;
    int blk = blockIdx.x;          // 0..15
    int t = threadIdx.x;           // 0..255
    const float* xb = x + (size_t)b * (CH * HW);
    int hw0 = blk * (HW / 16);     // 16384-wide chunk
    float accr = 0.f, accc = 0.f;
    #pragma unroll 4
    for (int j = 0; j < 16; ++j) {
        int hw = hw0 + j * 1024 + t * 4;
        float4 gr = *(const float4*)(Gr + hw);
        float4 gc = *(const float4*)(Gc + hw);
        float4 x0 = *(const float4*)(xb + hw);
        float4 x1 = *(const float4*)(xb + HW + hw);
        float4 x2 = *(const float4*)(xb + 2 * HW + hw);
        float sxx = x0.x + x1.x + x2.x;
        float sxy = x0.y + x1.y + x2.y;
        float sxz = x0.z + x1.z + x2.z;
        float sxw = x0.w + x1.w + x2.w;
        accr += gr.x * sxx + gr.y * sxy + gr.z * sxz + gr.w * sxw;
        accc += gc.x * sxx + gc.y * sxy + gc.z * sxz + gc.w * sxw;
    }
    // wave (64) reduce
    for (int off = 32; off > 0; off >>= 1) {
        accr += __shfl_down(accr, off);
        accc += __shfl_down(accc, off);
    }
    __shared__ float sr[4], sc[4];
    int wid = t >> 6;
    if ((t & 63) == 0) { sr[wid] = accr; sc[wid] = accc; }
    __syncthreads();
    if (t == 0) {
        float r = sr[0] + sr[1] + sr[2] + sr[3];
        float c = sc[0] + sc[1] + sc[2] + sc[3];
        partials[(b * 16 + blk) * 2 + 0] = r;
        partials[(b * 16 + blk) * 2 + 1] = c;
    }
}

__global__ void k_final(const float* __restrict__ partials, float* __restrict__ out) {
    int b = threadIdx.x;   // 0..63
    float r = 0.f, c = 0.f;
    for (int i = 0; i < 16; ++i) {
        r += partials[(b * 16 + i) * 2 + 0];
        c += partials[(b * 16 + i) * 2 + 1];
    }
    const float inv = 1.0f / (float)(CH * HW);   // 1/786432
    r *= inv; c *= inv;
    out[b * 2 + 0] = 1.0f / (1.0f + expf(-c));   // col_out first (stack order)
    out[b * 2 + 1] = 1.0f / (1.0f + expf(-r));
}

extern "C" void kernel_launch(void* const* d_in, const int* in_sizes, int n_in,
                              void* d_out, int out_size, void* d_ws, size_t ws_size,
                              hipStream_t stream) {
    const float* x   = (const float*)d_in[0];   // [64,3,512,512]
    const float* att = (const float*)d_in[1];   // [512,512]
    const float* rw  = (const float*)d_in[2];   // [512]
    const float* cw  = (const float*)d_in[3];   // [512]
    float* out = (float*)d_out;                 // [64,2]

    float* ws = (float*)d_ws;
    float* Dm = ws;                 // 262144
    float* Tr = ws + 1 * HW;        // 262144
    float* Tc = ws + 2 * HW;
    float* Gr = ws + 3 * HW;
    float* Gc = ws + 4 * HW;
    float* partials = ws + 5 * HW;  // 64*16*2 = 2048

    k_computeD<<<1024, 256, 0, stream>>>(Dm);
    k_stageA<<<1024, 256, 0, stream>>>(Dm, att, rw, cw, Tr, Tc);
    k_stageB<<<1024, 256, 0, stream>>>(Dm, Tr, Tc, Gr, Gc);
    dim3 g(16, 64);
    k_reduce<<<g, 256, 0, stream>>>(x, Gr, Gc, partials);
    k_final<<<1, 64, 0, stream>>>(partials, out);
}